// Round 1
// 2763.642 us; speedup vs baseline: 1.6054x; 1.6054x over previous
//
#include <hip/hip_runtime.h>
#include <cmath>

#define N_NODES 50000
#define N_EDGES 800000
#define IN_FEAT 256
#define HIDDEN  512
#define NUM_LAYERS 4

typedef __attribute__((ext_vector_type(8))) short short8;
typedef __attribute__((ext_vector_type(4))) float floatx4;
typedef __attribute__((address_space(1))) unsigned short GUS;
typedef __attribute__((address_space(3))) unsigned short LUS;

__device__ __forceinline__ unsigned short f2bf(float f) {
    unsigned u = __float_as_uint(f);
    return (unsigned short)((u + 0x7fffu + ((u >> 16) & 1u)) >> 16);
}
__device__ __forceinline__ float bf2f(unsigned short h) {
    return __uint_as_float(((unsigned)h) << 16);
}

// ---------------- CSR build ----------------

__global__ void hist_kernel(const int* __restrict__ dst, int* __restrict__ counts, int E) {
    int e = blockIdx.x * blockDim.x + threadIdx.x;
    if (e < E) atomicAdd(&counts[dst[e]], 1);
}

__global__ __launch_bounds__(1024) void scan_kernel(int* __restrict__ cnt, int* __restrict__ offs, int n) {
    __shared__ int partial[1024];
    const int tid = threadIdx.x;
    const int chunk = (n + 1023) / 1024;
    int start = tid * chunk;
    int end = start + chunk; if (end > n) end = n; if (start > n) start = n;
    int sum = 0;
    for (int i = start; i < end; ++i) sum += cnt[i];
    partial[tid] = sum;
    __syncthreads();
    for (int off = 1; off < 1024; off <<= 1) {
        int v = (tid >= off) ? partial[tid - off] : 0;
        __syncthreads();
        partial[tid] += v;
        __syncthreads();
    }
    int base = (tid == 0) ? 0 : partial[tid - 1];
    for (int i = start; i < end; ++i) {
        int c = cnt[i];
        offs[i] = base;
        cnt[i]  = base;
        base += c;
    }
    if (tid == 1023) offs[n] = partial[1023];
}

__global__ void fill_kernel(const int* __restrict__ src, const int* __restrict__ dst,
                            int* __restrict__ cursor, int* __restrict__ srcs, int E) {
    int e = blockIdx.x * blockDim.x + threadIdx.x;
    if (e < E) {
        int pos = atomicAdd(&cursor[dst[e]], 1);
        srcs[pos] = src[e];
    }
}

// ---------------- fp32 -> bf16 hi/lo split ----------------

__global__ void split_kernel(const float* __restrict__ in, unsigned short* __restrict__ hi,
                             unsigned short* __restrict__ lo, int n4) {
    int i = blockIdx.x * blockDim.x + threadIdx.x;
    int stride = gridDim.x * blockDim.x;
    for (; i < n4; i += stride) {
        float4 v = ((const float4*)in)[i];
        ushort4 h, l;
        h.x = f2bf(v.x); l.x = f2bf(v.x - bf2f(h.x));
        h.y = f2bf(v.y); l.y = f2bf(v.y - bf2f(h.y));
        h.z = f2bf(v.z); l.z = f2bf(v.z - bf2f(h.z));
        h.w = f2bf(v.w); l.w = f2bf(v.w - bf2f(h.w));
        ((ushort4*)hi)[i] = h;
        ((ushort4*)lo)[i] = l;
    }
}

// ---------------- aggregation: one wave per node, bf16 hi/lo output ----------------

__global__ __launch_bounds__(256) void aggr_hl_kernel(const float* __restrict__ s,
                                                      const int* __restrict__ offs,
                                                      const int* __restrict__ srcs,
                                                      unsigned short* __restrict__ ah,
                                                      unsigned short* __restrict__ al) {
    int node = blockIdx.x * 4 + (threadIdx.x >> 6);
    if (node >= N_NODES) return;
    int lane = threadIdx.x & 63;
    int beg = offs[node], end = offs[node + 1];
    float4 acc0 = make_float4(0.f, 0.f, 0.f, 0.f);
    float4 acc1 = make_float4(0.f, 0.f, 0.f, 0.f);
    for (int e = beg; e < end; ++e) {
        const float4* row = (const float4*)(s + (size_t)srcs[e] * HIDDEN);
        float4 v0 = row[lane * 2];
        float4 v1 = row[lane * 2 + 1];
        acc0.x += v0.x; acc0.y += v0.y; acc0.z += v0.z; acc0.w += v0.w;
        acc1.x += v1.x; acc1.y += v1.y; acc1.z += v1.z; acc1.w += v1.w;
    }
    ushort4 h0, l0, h1, l1;
    h0.x = f2bf(acc0.x); l0.x = f2bf(acc0.x - bf2f(h0.x));
    h0.y = f2bf(acc0.y); l0.y = f2bf(acc0.y - bf2f(h0.y));
    h0.z = f2bf(acc0.z); l0.z = f2bf(acc0.z - bf2f(h0.z));
    h0.w = f2bf(acc0.w); l0.w = f2bf(acc0.w - bf2f(h0.w));
    h1.x = f2bf(acc1.x); l1.x = f2bf(acc1.x - bf2f(h1.x));
    h1.y = f2bf(acc1.y); l1.y = f2bf(acc1.y - bf2f(h1.y));
    h1.z = f2bf(acc1.z); l1.z = f2bf(acc1.z - bf2f(h1.z));
    h1.w = f2bf(acc1.w); l1.w = f2bf(acc1.w - bf2f(h1.w));
    size_t o = (size_t)node * HIDDEN + lane * 8;
    *(ushort4*)(ah + o)     = h0;
    *(ushort4*)(ah + o + 4) = h1;
    *(ushort4*)(al + o)     = l0;
    *(ushort4*)(al + o + 4) = l1;
}

// ---------------- bf16x3 MFMA GEMM ----------------
// out = a*tanh(A1@B1^T + A2@B2^T) + (1-a)*s, split-precision:
// A ~ Ah+Al, B ~ Bh+Bl, acc += Ah*Bh + Al*Bh + Ah*Bl  (Al*Bl dropped, ~2^-18 rel)
// 128x128 tile, 4 waves (2x2), 16x16x32 bf16 MFMA, 4x4 frags/wave.
// LDS tiles linear [128][32] bf16, staged via global_load_lds width=16 with the
// global source column pre-swizzled by c ^= (row>>1)&3 (read applies same XOR)
// so fragment ds_read_b128 is 2-way (free) instead of 8-way conflicted.

__global__ __launch_bounds__(256) void gemm_mfma(
    const unsigned short* __restrict__ Ah1, const unsigned short* __restrict__ Al1,
    const unsigned short* __restrict__ Bh1, const unsigned short* __restrict__ Bl1, int K1,
    const unsigned short* __restrict__ Ah2, const unsigned short* __restrict__ Al2,
    const unsigned short* __restrict__ Bh2, const unsigned short* __restrict__ Bl2,
    const float* __restrict__ sl, const float* __restrict__ leak,
    float* __restrict__ out, unsigned short* __restrict__ outh,
    unsigned short* __restrict__ outl, int write_hl)
{
    __shared__ alignas(16) unsigned short As_h[128 * 32];
    __shared__ alignas(16) unsigned short As_l[128 * 32];
    __shared__ alignas(16) unsigned short Bs_h[128 * 32];
    __shared__ alignas(16) unsigned short Bs_l[128 * 32];

    const int tid  = threadIdx.x;
    const int wave = tid >> 6;
    const int lane = tid & 63;
    const int m0 = blockIdx.y * 128;
    const int j0 = blockIdx.x * 128;
    const int wr = wave >> 1, wc = wave & 1;

    floatx4 acc[4][4];
#pragma unroll
    for (int i = 0; i < 4; ++i)
#pragma unroll
        for (int j = 0; j < 4; ++j) acc[i][j] = (floatx4){0.f, 0.f, 0.f, 0.f};

    unsigned short* myTile = (wave == 0) ? As_h : (wave == 1) ? As_l
                           : (wave == 2) ? Bs_h : Bs_l;
    const int gbase = (wave < 2) ? m0 : j0;
    const int srow  = lane >> 2;   // row within 16-row chunk
    const int cslot = lane & 3;    // 16B slot within 64B row

#pragma unroll 1
    for (int seg = 0; seg < 2; ++seg) {
        const unsigned short* Gt =
            (wave == 0) ? (seg ? Ah2 : Ah1) :
            (wave == 1) ? (seg ? Al2 : Al1) :
            (wave == 2) ? (seg ? Bh2 : Bh1) :
                          (seg ? Bl2 : Bl1);
        const int K = seg ? HIDDEN : K1;
#pragma unroll 1
        for (int kb = 0; kb < K; kb += 32) {
            // stage this wave's 8KB tile: 8 chunks x 16 rows x 64B
#pragma unroll
            for (int i = 0; i < 8; ++i) {
                int row = i * 16 + srow;
                int cg  = cslot ^ ((row >> 1) & 3);       // pre-swizzled source column
                int grow = gbase + row;
                if (wave < 2 && grow > N_NODES - 1) grow = N_NODES - 1;
                const unsigned short* gp = Gt + (size_t)grow * K + (kb + cg * 8);
                __builtin_amdgcn_global_load_lds((GUS*)gp, (LUS*)(myTile + i * 512), 16, 0, 0);
            }
            __syncthreads();

            short8 a_h[4], a_l[4], b_h[4], b_l[4];
            const int rl = lane & 15, kg = lane >> 4;
#pragma unroll
            for (int f = 0; f < 4; ++f) {
                int ar = wr * 64 + f * 16 + rl;
                int ao = ar * 32 + ((kg ^ ((ar >> 1) & 3)) << 3);
                a_h[f] = *(const short8*)&As_h[ao];
                a_l[f] = *(const short8*)&As_l[ao];
                int br = wc * 64 + f * 16 + rl;
                int bo = br * 32 + ((kg ^ ((br >> 1) & 3)) << 3);
                b_h[f] = *(const short8*)&Bs_h[bo];
                b_l[f] = *(const short8*)&Bs_l[bo];
            }
#pragma unroll
            for (int i = 0; i < 4; ++i)
#pragma unroll
                for (int j = 0; j < 4; ++j) {
                    acc[i][j] = __builtin_amdgcn_mfma_f32_16x16x32_bf16(a_h[i], b_h[j], acc[i][j], 0, 0, 0);
                    acc[i][j] = __builtin_amdgcn_mfma_f32_16x16x32_bf16(a_l[i], b_h[j], acc[i][j], 0, 0, 0);
                    acc[i][j] = __builtin_amdgcn_mfma_f32_16x16x32_bf16(a_h[i], b_l[j], acc[i][j], 0, 0, 0);
                }
            __syncthreads();
        }
    }

    // epilogue: C/D frag layout col=lane&15, row=(lane>>4)*4+reg  [m89-verified]
    const float a = leak[0], om = 1.0f - a;
    const int rl = lane & 15, rg = lane >> 4;
#pragma unroll
    for (int i = 0; i < 4; ++i) {
#pragma unroll
        for (int r = 0; r < 4; ++r) {
            int m = m0 + wr * 64 + i * 16 + rg * 4 + r;
            if (m >= N_NODES) continue;
#pragma unroll
            for (int j = 0; j < 4; ++j) {
                int c = j0 + wc * 64 + j * 16 + rl;
                size_t idx = (size_t)m * HIDDEN + c;
                float v = a * tanhf(acc[i][j][r]) + om * sl[idx];
                out[idx] = v;
                if (write_hl) {
                    unsigned short h = f2bf(v);
                    outh[idx] = h;
                    outl[idx] = f2bf(v - bf2f(h));
                }
            }
        }
    }
}

// ---------------- fallback fp32 path (previous verified kernels) ----------------

__global__ __launch_bounds__(256) void aggr_kernel(const float* __restrict__ s,
                                                   const int* __restrict__ offs,
                                                   const int* __restrict__ srcs,
                                                   float* __restrict__ aggr) {
    int node = blockIdx.x * 4 + (threadIdx.x >> 6);
    if (node >= N_NODES) return;
    int lane = threadIdx.x & 63;
    int beg = offs[node], end = offs[node + 1];
    float4 acc0 = make_float4(0.f, 0.f, 0.f, 0.f);
    float4 acc1 = make_float4(0.f, 0.f, 0.f, 0.f);
    for (int e = beg; e < end; ++e) {
        const float4* row = (const float4*)(s + (size_t)srcs[e] * HIDDEN);
        float4 v0 = row[lane * 2];
        float4 v1 = row[lane * 2 + 1];
        acc0.x += v0.x; acc0.y += v0.y; acc0.z += v0.z; acc0.w += v0.w;
        acc1.x += v1.x; acc1.y += v1.y; acc1.z += v1.z; acc1.w += v1.w;
    }
    float4* o = (float4*)(aggr + (size_t)node * HIDDEN);
    o[lane * 2]     = acc0;
    o[lane * 2 + 1] = acc1;
}

__global__ __launch_bounds__(256) void gemm_kernel(const float* __restrict__ A1,
                                                   const float* __restrict__ B1, int K1,
                                                   const float* __restrict__ A2,
                                                   const float* __restrict__ B2,
                                                   const float* __restrict__ sl,
                                                   const float* __restrict__ leak,
                                                   float* __restrict__ out) {
    const int BK = 16;
    __shared__ float As[BK][132];
    __shared__ float Bs[BK][132];
    const int tid = threadIdx.x;
    const int tx = tid & 15;
    const int ty = tid >> 4;
    const int m0 = blockIdx.y * 128;
    const int j0 = blockIdx.x * 128;

    float acc[8][8];
#pragma unroll
    for (int i = 0; i < 8; ++i)
#pragma unroll
        for (int j = 0; j < 8; ++j) acc[i][j] = 0.f;

#pragma unroll 1
    for (int seg = 0; seg < 2; ++seg) {
        const float* A = seg ? A2 : A1;
        const float* B = seg ? B2 : B1;
        const int K = seg ? HIDDEN : K1;
#pragma unroll 1
        for (int kb = 0; kb < K; kb += BK) {
#pragma unroll
            for (int rep = 0; rep < 2; ++rep) {
                int f   = tid + rep * 256;
                int row = f >> 2;
                int k4  = (f & 3) * 4;
                int gr  = m0 + row;
                float4 v = make_float4(0.f, 0.f, 0.f, 0.f);
                if (gr < N_NODES) v = *(const float4*)(A + (size_t)gr * K + kb + k4);
                As[k4 + 0][row] = v.x; As[k4 + 1][row] = v.y;
                As[k4 + 2][row] = v.z; As[k4 + 3][row] = v.w;
                float4 w = *(const float4*)(B + (size_t)(j0 + row) * K + kb + k4);
                Bs[k4 + 0][row] = w.x; Bs[k4 + 1][row] = w.y;
                Bs[k4 + 2][row] = w.z; Bs[k4 + 3][row] = w.w;
            }
            __syncthreads();
#pragma unroll
            for (int k = 0; k < BK; ++k) {
                float4 a0 = *(const float4*)&As[k][ty * 4];
                float4 a1 = *(const float4*)&As[k][64 + ty * 4];
                float4 b0 = *(const float4*)&Bs[k][tx * 4];
                float4 b1 = *(const float4*)&Bs[k][64 + tx * 4];
                float av[8] = {a0.x, a0.y, a0.z, a0.w, a1.x, a1.y, a1.z, a1.w};
                float bv[8] = {b0.x, b0.y, b0.z, b0.w, b1.x, b1.y, b1.z, b1.w};
#pragma unroll
                for (int i = 0; i < 8; ++i)
#pragma unroll
                    for (int j = 0; j < 8; ++j)
                        acc[i][j] = fmaf(av[i], bv[j], acc[i][j]);
            }
            __syncthreads();
        }
    }

    const float a  = leak[0];
    const float om = 1.0f - a;
#pragma unroll
    for (int ih = 0; ih < 2; ++ih) {
#pragma unroll
        for (int i = 0; i < 4; ++i) {
            int gr = m0 + ih * 64 + ty * 4 + i;
            if (gr >= N_NODES) continue;
#pragma unroll
            for (int jh = 0; jh < 2; ++jh) {
                int gc = j0 + jh * 64 + tx * 4;
                float4 sv = *(const float4*)(sl + (size_t)gr * HIDDEN + gc);
                float4 r;
                r.x = a * tanhf(acc[ih * 4 + i][jh * 4 + 0]) + om * sv.x;
                r.y = a * tanhf(acc[ih * 4 + i][jh * 4 + 1]) + om * sv.y;
                r.z = a * tanhf(acc[ih * 4 + i][jh * 4 + 2]) + om * sv.z;
                r.w = a * tanhf(acc[ih * 4 + i][jh * 4 + 3]) + om * sv.w;
                *(float4*)(out + (size_t)gr * HIDDEN + gc) = r;
            }
        }
    }
}

// ---------------- launch ----------------

extern "C" void kernel_launch(void* const* d_in, const int* in_sizes, int n_in,
                              void* d_out, int out_size, void* d_ws, size_t ws_size,
                              hipStream_t stream) {
    const int*   edge   = (const int*)d_in[0];
    const float* x      = (const float*)d_in[1];
    const float* states = (const float*)d_in[2];
    const float* Wi0    = (const float*)d_in[3];
    const float* WiR    = (const float*)d_in[4];
    const float* Wr     = (const float*)d_in[5];
    const float* leak   = (const float*)d_in[6];
    float* out = (float*)d_out;

    const int E = N_EDGES, N = N_NODES;
    const int* src = edge;
    const int* dst = edge + E;

    char* ws = (char*)d_ws;
    size_t off = 0;
    auto alloc = [&](size_t bytes) -> char* {
        char* p = ws + off;
        off += (bytes + 255) & ~(size_t)255;
        return p;
    };
    int* cursor = (int*)alloc((size_t)N * 4);
    int* offs   = (int*)alloc((size_t)(N + 1) * 4);
    int* srcs   = (int*)alloc((size_t)E * 4);
    unsigned short* xh   = (unsigned short*)alloc((size_t)N * IN_FEAT * 2);
    unsigned short* xl   = (unsigned short*)alloc((size_t)N * IN_FEAT * 2);
    unsigned short* wi0h = (unsigned short*)alloc((size_t)HIDDEN * IN_FEAT * 2);
    unsigned short* wi0l = (unsigned short*)alloc((size_t)HIDDEN * IN_FEAT * 2);
    unsigned short* wiRh = (unsigned short*)alloc((size_t)3 * HIDDEN * HIDDEN * 2);
    unsigned short* wiRl = (unsigned short*)alloc((size_t)3 * HIDDEN * HIDDEN * 2);
    unsigned short* wrh  = (unsigned short*)alloc((size_t)4 * HIDDEN * HIDDEN * 2);
    unsigned short* wrl  = (unsigned short*)alloc((size_t)4 * HIDDEN * HIDDEN * 2);
    unsigned short *bufh[3], *bufl[3];
    for (int b = 0; b < 3; ++b) {
        bufh[b] = (unsigned short*)alloc((size_t)N * HIDDEN * 2);
        bufl[b] = (unsigned short*)alloc((size_t)N * HIDDEN * 2);
    }

    if (off <= ws_size) {
        // -------- fast path: bf16x3 MFMA --------
        hipMemsetAsync(cursor, 0, (size_t)N * sizeof(int), stream);
        hist_kernel<<<(E + 255) / 256, 256, 0, stream>>>(dst, cursor, E);
        scan_kernel<<<1, 1024, 0, stream>>>(cursor, offs, N);
        fill_kernel<<<(E + 255) / 256, 256, 0, stream>>>(src, dst, cursor, srcs, E);

        auto splitN = [&](const float* p, unsigned short* h, unsigned short* l, int n4) {
            int blocks = (n4 + 255) / 256; if (blocks > 2048) blocks = 2048;
            split_kernel<<<blocks, 256, 0, stream>>>(p, h, l, n4);
        };
        splitN(x,   xh,   xl,   N * IN_FEAT / 4);
        splitN(Wi0, wi0h, wi0l, HIDDEN * IN_FEAT / 4);
        splitN(WiR, wiRh, wiRl, 3 * HIDDEN * HIDDEN / 4);
        splitN(Wr,  wrh,  wrl,  4 * HIDDEN * HIDDEN / 4);

        // buffer rotation: gemm l reads {inp, aggr}, writes out-hi/lo; all disjoint
        const int aggrIdx[4] = {2, 1, 0, 2};
        const int outIdx[4]  = {0, 2, 1, 0};   // l=3 write_hl=0 (dest unused)
        const unsigned short* inph = xh;
        const unsigned short* inpl = xl;
        dim3 ggrid(HIDDEN / 128, (N + 127) / 128);
        for (int l = 0; l < NUM_LAYERS; ++l) {
            const float* slp = states + (size_t)l * N * HIDDEN;
            unsigned short* agh = bufh[aggrIdx[l]];
            unsigned short* agl = bufl[aggrIdx[l]];
            aggr_hl_kernel<<<(N + 3) / 4, 256, 0, stream>>>(slp, offs, srcs, agh, agl);
            const unsigned short* b1h = (l == 0) ? wi0h : wiRh + (size_t)(l - 1) * HIDDEN * HIDDEN;
            const unsigned short* b1l = (l == 0) ? wi0l : wiRl + (size_t)(l - 1) * HIDDEN * HIDDEN;
            int K1 = (l == 0) ? IN_FEAT : HIDDEN;
            const unsigned short* b2h = wrh + (size_t)l * HIDDEN * HIDDEN;
            const unsigned short* b2l = wrl + (size_t)l * HIDDEN * HIDDEN;
            int whl = (l < NUM_LAYERS - 1) ? 1 : 0;
            gemm_mfma<<<ggrid, 256, 0, stream>>>(inph, inpl, b1h, b1l, K1,
                                                 agh, agl, b2h, b2l,
                                                 slp, leak,
                                                 out + (size_t)l * N * HIDDEN,
                                                 bufh[outIdx[l]], bufl[outIdx[l]], whl);
            inph = bufh[outIdx[l]];
            inpl = bufl[outIdx[l]];
        }
    } else {
        // -------- fallback: previous verified fp32 path --------
        int* cursorF = (int*)ws;
        int* offsF   = cursorF + N;
        int* srcsF   = offsF + N + 1;
        size_t off_aggr = (((size_t)(N + (N + 1) + E)) * sizeof(int) + 255) & ~(size_t)255;
        float* aggr = (float*)(ws + off_aggr);

        hipMemsetAsync(cursorF, 0, (size_t)N * sizeof(int), stream);
        hist_kernel<<<(E + 255) / 256, 256, 0, stream>>>(dst, cursorF, E);
        scan_kernel<<<1, 1024, 0, stream>>>(cursorF, offsF, N);
        fill_kernel<<<(E + 255) / 256, 256, 0, stream>>>(src, dst, cursorF, srcsF, E);

        dim3 ggrid(HIDDEN / 128, (N + 127) / 128);
        for (int l = 0; l < NUM_LAYERS; ++l) {
            const float* slp = states + (size_t)l * N * HIDDEN;
            aggr_kernel<<<(N + 3) / 4, 256, 0, stream>>>(slp, offsF, srcsF, aggr);
            const float* A1 = (l == 0) ? x : out + (size_t)(l - 1) * N * HIDDEN;
            const float* B1 = (l == 0) ? Wi0 : WiR + (size_t)(l - 1) * HIDDEN * HIDDEN;
            int K1 = (l == 0) ? IN_FEAT : HIDDEN;
            const float* B2 = Wr + (size_t)l * HIDDEN * HIDDEN;
            gemm_kernel<<<ggrid, 256, 0, stream>>>(A1, B1, K1, aggr, B2, slp, leak,
                                                   out + (size_t)l * N * HIDDEN);
        }
    }
}